// Round 1
// baseline (5333.424 us; speedup 1.0000x reference)
//
#include <hip/hip_runtime.h>
#include <math.h>

// Problem constants (fixed by the reference setup)
constexpr int BATCH = 4096;
constexpr int SEQ_T = 72;
constexpr int FDIM  = 64;
constexpr int UNITS = 256;
constexpr int U4    = 1024;

// Step-kernel tiling
constexpr int BM = 32;   // batch rows per block
constexpr int BU = 64;   // units per block (covers 4*BU=256 z-columns)
constexpr int KC = 32;   // k-chunk
constexpr int KTOT = FDIM + UNITS; // 320

__device__ __forceinline__ float sigmoid_fast(float x) {
    return 1.0f / (1.0f + __expf(-x));
}
__device__ __forceinline__ float tanh_fast(float x) {
    // overflow-safe: e^(2|x|) -> inf gives t -> 1
    float ax = fabsf(x);
    float e  = __expf(2.0f * ax);
    float t  = 1.0f - 2.0f / (e + 1.0f);
    return copysignf(t, x);
}

// One LSTM step: z = [x|h_in] @ [W;U] + b ; gates ; c,h update.
// grid = (BATCH/BM, UNITS/BU), block = 256
__global__ __launch_bounds__(256, 2) void lstm_step_kernel(
    const float* __restrict__ x, int x_stride,     // x rows at x + b*x_stride, length FDIM
    const float* __restrict__ h_in,                // [B][UNITS]
    float* __restrict__ h_out,                     // [B][UNITS]
    float* __restrict__ c_inout,                   // [B][UNITS] (in-place safe)
    const float* __restrict__ W,                   // [FDIM][U4]
    const float* __restrict__ U,                   // [UNITS][U4]
    const float* __restrict__ bias)                // [U4]
{
    __shared__ float xh[KC][BM + 1];       // +1 pad: conflict-free transpose store
    __shared__ float wt[KC][4 * BU];       // [k][g*BU + uu]

    const int tid = threadIdx.x;
    const int bb = blockIdx.x * BM;
    const int ub = blockIdx.y * BU;

    const int bg = tid >> 4;    // 0..15 -> batch pair
    const int ug = tid & 15;    // 0..15 -> 4-unit group
    const int b0 = bg * 2;

    float acc[2][4][4];
    #pragma unroll
    for (int i = 0; i < 2; ++i)
        #pragma unroll
        for (int g = 0; g < 4; ++g)
            #pragma unroll
            for (int j = 0; j < 4; ++j) acc[i][g][j] = 0.0f;

    for (int k0 = 0; k0 < KTOT; k0 += KC) {
        // ---- stage xh chunk [KC][BM] (1024 elems, 4/thread) ----
        #pragma unroll
        for (int i = 0; i < (KC * BM) / 256; ++i) {
            int lin = i * 256 + tid;
            int bl  = lin >> 5;          // 0..31 (batch-major for coalesced global read)
            int kk  = lin & 31;
            int kg  = k0 + kk;
            float v;
            if (kg < FDIM) v = x[(size_t)(bb + bl) * x_stride + kg];
            else           v = h_in[(size_t)(bb + bl) * UNITS + (kg - FDIM)];
            xh[kk][bl] = v;
        }
        // ---- stage weight chunk [KC][4*BU] (8192 elems = 2048 float4, 8/thread) ----
        #pragma unroll
        for (int i = 0; i < 8; ++i) {
            int lin = i * 256 + tid;     // 0..2047 (float4 index)
            int kk  = lin >> 6;          // 64 float4 per k-row
            int rem = lin & 63;          // g*16 + u4
            int g   = rem >> 4;
            int u4  = rem & 15;
            int kg  = k0 + kk;
            int col = g * UNITS + ub + u4 * 4;
            const float* src = (kg < FDIM) ? (W + (size_t)kg * U4 + col)
                                           : (U + (size_t)(kg - FDIM) * U4 + col);
            float4 v = *reinterpret_cast<const float4*>(src);
            *reinterpret_cast<float4*>(&wt[kk][rem * 4]) = v;
        }
        __syncthreads();

        // ---- accumulate ----
        #pragma unroll
        for (int k = 0; k < KC; ++k) {
            float xv0 = xh[k][b0];
            float xv1 = xh[k][b0 + 1];
            #pragma unroll
            for (int g = 0; g < 4; ++g) {
                float4 wv = *reinterpret_cast<const float4*>(&wt[k][g * BU + ug * 4]);
                acc[0][g][0] += xv0 * wv.x;
                acc[0][g][1] += xv0 * wv.y;
                acc[0][g][2] += xv0 * wv.z;
                acc[0][g][3] += xv0 * wv.w;
                acc[1][g][0] += xv1 * wv.x;
                acc[1][g][1] += xv1 * wv.y;
                acc[1][g][2] += xv1 * wv.z;
                acc[1][g][3] += xv1 * wv.w;
            }
        }
        __syncthreads();
    }

    // ---- bias + gates + state update (gate order: i, f, g, o) ----
    const int ucol = ub + ug * 4;
    float bias4[4][4];
    #pragma unroll
    for (int g = 0; g < 4; ++g) {
        float4 bv = *reinterpret_cast<const float4*>(&bias[g * UNITS + ucol]);
        bias4[g][0] = bv.x; bias4[g][1] = bv.y; bias4[g][2] = bv.z; bias4[g][3] = bv.w;
    }
    #pragma unroll
    for (int bi = 0; bi < 2; ++bi) {
        int brow = bb + b0 + bi;
        float4 cold = *reinterpret_cast<const float4*>(&c_inout[(size_t)brow * UNITS + ucol]);
        float ca[4] = {cold.x, cold.y, cold.z, cold.w};
        float hn[4], cn[4];
        #pragma unroll
        for (int j = 0; j < 4; ++j) {
            float zi = acc[bi][0][j] + bias4[0][j];
            float zf = acc[bi][1][j] + bias4[1][j];
            float zg = acc[bi][2][j] + bias4[2][j];
            float zo = acc[bi][3][j] + bias4[3][j];
            float ig = sigmoid_fast(zi);
            float fg = sigmoid_fast(zf);
            float og = sigmoid_fast(zo);
            float cv = fg * ca[j] + ig * tanh_fast(zg);
            cn[j] = cv;
            hn[j] = og * tanh_fast(cv);
        }
        *reinterpret_cast<float4*>(&c_inout[(size_t)brow * UNITS + ucol]) =
            make_float4(cn[0], cn[1], cn[2], cn[3]);
        *reinterpret_cast<float4*>(&h_out[(size_t)brow * UNITS + ucol]) =
            make_float4(hn[0], hn[1], hn[2], hn[3]);
    }
}

// pred = h @ Wd + bd ; also scatter into out[:, s, :]
// grid = BATCH/4, block = 256 (4 batch rows x 64 features)
__global__ __launch_bounds__(256, 2) void dense_kernel(
    const float* __restrict__ h,    // [B][UNITS]
    const float* __restrict__ Wd,   // [UNITS][FDIM]
    const float* __restrict__ bd,   // [FDIM]
    float* __restrict__ pred,       // [B][FDIM]
    float* __restrict__ out,        // [B][out_steps][FDIM]
    int s, int out_steps)
{
    __shared__ float wds[UNITS][FDIM];  // 64 KB
    const int tid = threadIdx.x;
    #pragma unroll
    for (int i = 0; i < 16; ++i) {
        int lin = i * 256 + tid;        // float4 index, 0..4095
        int r   = lin >> 4;
        int c4  = lin & 15;
        *reinterpret_cast<float4*>(&wds[r][c4 * 4]) =
            *reinterpret_cast<const float4*>(&Wd[(size_t)r * FDIM + c4 * 4]);
    }
    __syncthreads();

    const int f    = tid & 63;
    const int bl   = tid >> 6;
    const int brow = blockIdx.x * 4 + bl;
    const float* hrow = h + (size_t)brow * UNITS;

    float sum = 0.0f;
    #pragma unroll 8
    for (int u = 0; u < UNITS; ++u) sum += hrow[u] * wds[u][f];
    sum += bd[f];

    pred[(size_t)brow * FDIM + f] = sum;
    out[((size_t)brow * out_steps + s) * FDIM + f] = sum;
}

extern "C" void kernel_launch(void* const* d_in, const int* in_sizes, int n_in,
                              void* d_out, int out_size, void* d_ws, size_t ws_size,
                              hipStream_t stream) {
    const float* inputs = (const float*)d_in[0];
    const float* W      = (const float*)d_in[1];
    const float* U      = (const float*)d_in[2];
    const float* b      = (const float*)d_in[3];
    const float* Wd     = (const float*)d_in[4];
    const float* bd     = (const float*)d_in[5];
    float* out = (float*)d_out;
    const int out_steps = out_size / (BATCH * FDIM);   // = 24

    float* h0   = (float*)d_ws;
    float* h1   = h0 + (size_t)BATCH * UNITS;
    float* c    = h1 + (size_t)BATCH * UNITS;
    float* pred = c  + (size_t)BATCH * UNITS;

    hipMemsetAsync(h0, 0, (size_t)BATCH * UNITS * sizeof(float), stream);
    hipMemsetAsync(c,  0, (size_t)BATCH * UNITS * sizeof(float), stream);

    dim3 sgrid(BATCH / BM, UNITS / BU);
    dim3 sblock(256);
    dim3 dgrid(BATCH / 4);

    const float* hin = h0;
    float* hout = h1;

    // ---- warmup over input sequence ----
    for (int t = 0; t < SEQ_T; ++t) {
        lstm_step_kernel<<<sgrid, sblock, 0, stream>>>(
            inputs + (size_t)t * FDIM, SEQ_T * FDIM, hin, hout, c, W, U, b);
        const float* tmp = hin; hin = hout; hout = (float*)tmp;
    }
    dense_kernel<<<dgrid, 256, 0, stream>>>(hin, Wd, bd, pred, out, 0, out_steps);

    // ---- autoregressive decode ----
    for (int s = 1; s < out_steps; ++s) {
        lstm_step_kernel<<<sgrid, sblock, 0, stream>>>(
            pred, FDIM, hin, hout, c, W, U, b);
        const float* tmp = hin; hin = hout; hout = (float*)tmp;
        dense_kernel<<<dgrid, 256, 0, stream>>>(hin, Wd, bd, pred, out, s, out_steps);
    }
}

// Round 2
// 1458.937 us; speedup vs baseline: 3.6557x; 3.6557x over previous
//
#include <hip/hip_runtime.h>
#include <math.h>

// ---------- problem constants ----------
constexpr int SEQ_T = 72;
constexpr int FDIM  = 64;
constexpr int UNITS = 256;
constexpr int U4    = 1024;
constexpr int KTOT  = FDIM + UNITS;   // 320
constexpr int BM    = 64;             // batch rows per block
constexpr int NU    = 64;             // units per block (cols = 4 gates x NU = 256)
constexpr int NKC   = KTOT / 32;      // 10 k-chunks of 32

using short8 = __attribute__((ext_vector_type(8))) short;
using f32x4  = __attribute__((ext_vector_type(4))) float;

__device__ __forceinline__ float sigmoid_fast(float x) {
    return 1.0f / (1.0f + __expf(-x));
}
__device__ __forceinline__ float tanh_fast(float x) {
    float ax = fabsf(x);
    float e  = __expf(2.0f * ax);
    float t  = 1.0f - 2.0f / (e + 1.0f);
    return copysignf(t, x);
}
__device__ __forceinline__ unsigned short f2bf(float f) {
    union { float f; unsigned u; } v; v.f = f;
    unsigned r = (v.u + 0x7FFFu + ((v.u >> 16) & 1u)) >> 16;   // RNE
    return (unsigned short)r;
}

// ---------- prep: Wt[col][k] bf16, col in [0,1024), k in [0,320) ----------
// k < 64 -> W[k][col]; else U[k-64][col]
__global__ void prep_wt(const float* __restrict__ W, const float* __restrict__ U,
                        unsigned short* __restrict__ Wt) {
    int k = blockIdx.x;               // 0..319
    #pragma unroll
    for (int i = 0; i < 4; ++i) {
        int col = i * 256 + threadIdx.x;
        float v = (k < FDIM) ? W[(size_t)k * U4 + col] : U[(size_t)(k - FDIM) * U4 + col];
        Wt[(size_t)col * KTOT + k] = f2bf(v);
    }
}

// ---------- prep: Wdt[f][u] bf16 from Wd[u][f] fp32 ----------
__global__ void prep_wdt(const float* __restrict__ Wd, unsigned short* __restrict__ Wdt) {
    int f = blockIdx.x;               // 0..63
    int u = threadIdx.x;              // 0..255
    Wdt[(size_t)f * UNITS + u] = f2bf(Wd[(size_t)u * FDIM + f]);
}

// ---------- LSTM step: z = [x|h] @ [W;U] + b ; gates ; c,h update ----------
// grid (4096/BM, 256/NU) = (64,4); block 512 (8 waves: wm in 0..1, wu in 0..3)
__global__ __launch_bounds__(512, 1) void lstm_step_mfma(
    const float* __restrict__ x, int xstride,          // fp32 rows (inputs slice or pred)
    const unsigned short* __restrict__ hin,            // bf16 [B][256]
    unsigned short* __restrict__ hout,                 // bf16 [B][256]
    float* __restrict__ c_io,                          // fp32 [B][256]
    const unsigned short* __restrict__ Wt,             // bf16 [1024][320]
    const float* __restrict__ bias)                    // fp32 [1024]
{
    __shared__ unsigned short A[BM][328];              // 64 x (320 + 8 pad) bf16

    const int tid = threadIdx.x;
    const int bb  = blockIdx.x * BM;
    const int ub  = blockIdx.y * NU;

    // ---- stage x part: 64 rows x 64 floats -> bf16 (1 x 8-float chunk/thread) ----
    {
        int row = tid >> 3, cc = tid & 7;
        const float* src = x + (size_t)(bb + row) * xstride + cc * 8;
        float4 v0 = *reinterpret_cast<const float4*>(src);
        float4 v1 = *reinterpret_cast<const float4*>(src + 4);
        short8 pk;
        pk[0] = (short)f2bf(v0.x); pk[1] = (short)f2bf(v0.y);
        pk[2] = (short)f2bf(v0.z); pk[3] = (short)f2bf(v0.w);
        pk[4] = (short)f2bf(v1.x); pk[5] = (short)f2bf(v1.y);
        pk[6] = (short)f2bf(v1.z); pk[7] = (short)f2bf(v1.w);
        *reinterpret_cast<short8*>(&A[row][cc * 8]) = pk;
    }
    // ---- stage h part: 64 rows x 256 bf16 (4 x 16B chunks/thread) ----
    #pragma unroll
    for (int i = 0; i < 4; ++i) {
        int lin = i * 512 + tid;
        int row = lin >> 5, cc = lin & 31;
        *reinterpret_cast<short8*>(&A[row][64 + cc * 8]) =
            *reinterpret_cast<const short8*>(hin + (size_t)(bb + row) * UNITS + cc * 8);
    }
    __syncthreads();

    const int lane = tid & 63, w = tid >> 6;
    const int wm = w >> 2, wu = w & 3;
    const int l16 = lane & 15, hi4 = lane >> 4;

    // B-fragment base pointers (direct from L2-resident Wt), one per gate
    const unsigned short* bp[4];
    #pragma unroll
    for (int g = 0; g < 4; ++g)
        bp[g] = Wt + (size_t)(g * UNITS + ub + wu * 16 + l16) * KTOT + hi4 * 8;

    const unsigned short* arow0 = &A[wm * 32 + l16][hi4 * 8];
    const unsigned short* arow1 = &A[wm * 32 + 16 + l16][hi4 * 8];

    f32x4 acc[2][4];
    #pragma unroll
    for (int m = 0; m < 2; ++m)
        #pragma unroll
        for (int g = 0; g < 4; ++g)
            acc[m][g] = (f32x4){0.f, 0.f, 0.f, 0.f};

    // prefetch depth 2 (k-chunks)
    short8 breg[2][4];
    #pragma unroll
    for (int g = 0; g < 4; ++g) breg[0][g] = *reinterpret_cast<const short8*>(bp[g]);
    #pragma unroll
    for (int g = 0; g < 4; ++g) breg[1][g] = *reinterpret_cast<const short8*>(bp[g] + 32);

    #pragma unroll
    for (int kc = 0; kc < NKC; ++kc) {
        short8 a0 = *reinterpret_cast<const short8*>(arow0 + kc * 32);
        short8 a1 = *reinterpret_cast<const short8*>(arow1 + kc * 32);
        short8 bu[4];
        #pragma unroll
        for (int g = 0; g < 4; ++g) bu[g] = breg[kc & 1][g];
        if (kc + 2 < NKC) {
            #pragma unroll
            for (int g = 0; g < 4; ++g)
                breg[kc & 1][g] = *reinterpret_cast<const short8*>(bp[g] + (kc + 2) * 32);
        }
        #pragma unroll
        for (int g = 0; g < 4; ++g) {
            acc[0][g] = __builtin_amdgcn_mfma_f32_16x16x32_bf16(a0, bu[g], acc[0][g], 0, 0, 0);
            acc[1][g] = __builtin_amdgcn_mfma_f32_16x16x32_bf16(a1, bu[g], acc[1][g], 0, 0, 0);
        }
    }

    // ---- epilogue: bias + gates + state update (gate order i,f,g,o) ----
    const int u = ub + wu * 16 + l16;
    const float bi = bias[u], bf = bias[UNITS + u], bg = bias[2 * UNITS + u], bo = bias[3 * UNITS + u];
    #pragma unroll
    for (int m = 0; m < 2; ++m) {
        #pragma unroll
        for (int j = 0; j < 4; ++j) {
            int row = bb + wm * 32 + m * 16 + hi4 * 4 + j;
            float zi = acc[m][0][j] + bi;
            float zf = acc[m][1][j] + bf;
            float zg = acc[m][2][j] + bg;
            float zo = acc[m][3][j] + bo;
            float ig = sigmoid_fast(zi);
            float fg = sigmoid_fast(zf);
            float og = sigmoid_fast(zo);
            size_t idx = (size_t)row * UNITS + u;
            float cn = fg * c_io[idx] + ig * tanh_fast(zg);
            c_io[idx] = cn;
            hout[idx] = f2bf(og * tanh_fast(cn));
        }
    }
}

// ---------- dense head: pred = h @ Wd + bd (MFMA, 1 wave/block) ----------
// grid 4096/16 = 256 blocks, block 64
__global__ __launch_bounds__(64, 8) void dense_mfma(
    const unsigned short* __restrict__ h,    // bf16 [B][256]
    const unsigned short* __restrict__ Wdt,  // bf16 [64][256]
    const float* __restrict__ bd,
    float* __restrict__ pred,                // fp32 [B][64]
    float* __restrict__ out,                 // fp32 [B][out_steps][64]
    int s, int out_steps)
{
    const int lane = threadIdx.x;
    const int l16 = lane & 15, hi4 = lane >> 4;
    const int bb = blockIdx.x * 16;

    const unsigned short* ap = h + (size_t)(bb + l16) * UNITS + hi4 * 8;

    f32x4 acc[4];
    #pragma unroll
    for (int n = 0; n < 4; ++n) acc[n] = (f32x4){0.f, 0.f, 0.f, 0.f};

    #pragma unroll
    for (int kc = 0; kc < 8; ++kc) {
        short8 a = *reinterpret_cast<const short8*>(ap + kc * 32);
        #pragma unroll
        for (int n = 0; n < 4; ++n) {
            short8 b = *reinterpret_cast<const short8*>(
                Wdt + (size_t)(n * 16 + l16) * UNITS + kc * 32 + hi4 * 8);
            acc[n] = __builtin_amdgcn_mfma_f32_16x16x32_bf16(a, b, acc[n], 0, 0, 0);
        }
    }

    #pragma unroll
    for (int n = 0; n < 4; ++n) {
        int f = n * 16 + l16;
        float bdv = bd[f];
        #pragma unroll
        for (int j = 0; j < 4; ++j) {
            int row = bb + hi4 * 4 + j;
            float v = acc[n][j] + bdv;
            pred[(size_t)row * FDIM + f] = v;
            out[((size_t)row * out_steps + s) * FDIM + f] = v;
        }
    }
}

extern "C" void kernel_launch(void* const* d_in, const int* in_sizes, int n_in,
                              void* d_out, int out_size, void* d_ws, size_t ws_size,
                              hipStream_t stream) {
    const float* inputs = (const float*)d_in[0];
    const float* W      = (const float*)d_in[1];
    const float* U      = (const float*)d_in[2];
    const float* b      = (const float*)d_in[3];
    const float* Wd     = (const float*)d_in[4];
    const float* bd     = (const float*)d_in[5];
    float* out = (float*)d_out;

    const int BATCH = 4096;
    const int out_steps = out_size / (BATCH * FDIM);   // 24

    // ---- workspace carve ----
    char* ws = (char*)d_ws;
    unsigned short* h0  = (unsigned short*)(ws);                        // 2 MB
    unsigned short* h1  = (unsigned short*)(ws + (2u << 20));           // 2 MB
    float*          c   = (float*)(ws + (4u << 20));                    // 4 MB
    float*          pred= (float*)(ws + (8u << 20));                    // 1 MB
    unsigned short* Wt  = (unsigned short*)(ws + (9u << 20));           // 640 KB
    unsigned short* Wdt = (unsigned short*)(ws + (10u << 20));          // 32 KB

    // ---- prep ----
    prep_wt<<<KTOT, 256, 0, stream>>>(W, U, Wt);
    prep_wdt<<<FDIM, 256, 0, stream>>>(Wd, Wdt);
    hipMemsetAsync(h0, 0, (size_t)BATCH * UNITS * sizeof(unsigned short), stream);
    hipMemsetAsync(c,  0, (size_t)BATCH * UNITS * sizeof(float), stream);

    dim3 sgrid(BATCH / BM, UNITS / NU);   // (64, 4)
    dim3 sblock(512);
    dim3 dgrid(BATCH / 16);               // 256

    const unsigned short* hin = h0;
    unsigned short* hout = h1;

    // ---- warmup over input sequence ----
    for (int t = 0; t < SEQ_T; ++t) {
        lstm_step_mfma<<<sgrid, sblock, 0, stream>>>(
            inputs + (size_t)t * FDIM, SEQ_T * FDIM, hin, hout, c, Wt, b);
        const unsigned short* tmp = hin; hin = hout; hout = (unsigned short*)tmp;
    }
    dense_mfma<<<dgrid, 64, 0, stream>>>(hin, Wdt, bd, pred, out, 0, out_steps);

    // ---- autoregressive decode ----
    for (int s = 1; s < out_steps; ++s) {
        lstm_step_mfma<<<sgrid, sblock, 0, stream>>>(
            pred, FDIM, hin, hout, c, Wt, b);
        const unsigned short* tmp = hin; hin = hout; hout = (unsigned short*)tmp;
        dense_mfma<<<dgrid, 64, 0, stream>>>(hin, Wdt, bd, pred, out, s, out_steps);
    }
}